// Round 2
// baseline (89.128 us; speedup 1.0000x reference)
//
#include <hip/hip_runtime.h>
#include <hip/hip_bf16.h>

#define B_N 4096
#define E_N 64
#define D_N 1024
#define ROWS 8

typedef __bf16 bf16x8 __attribute__((ext_vector_type(8)));
typedef __bf16 bf16x4 __attribute__((ext_vector_type(4)));
typedef float f32x4 __attribute__((ext_vector_type(4)));

// ws layout (bytes):
// [0, 4096)        sinv   (1024 f32)
// [4096, 4352)     Ak     (64 f32)
// [4352, 135424)   sk_bf16 [64][1024]   (sigma_inv * keys, K-major)
// [135424, 266496) kT_bf16 [1024][64]   (raw keys transposed, K(=e)-major)

__global__ __launch_bounds__(256) void prep_kernel(
    const float* __restrict__ keys, const float* __restrict__ lsig,
    float* __restrict__ sinv, float* __restrict__ ak,
    __bf16* __restrict__ sk, __bf16* __restrict__ kT)
{
  __shared__ float red[4];
  __shared__ __bf16 tl[64][72];          // transpose tile, +8 pad
  const int bid = blockIdx.x;
  const int t = threadIdx.x;

  if (bid < 64) {
    // ---- per-expert: sinv, sk = sinv*keys (bf16), Ak = sum sinv*k^2 ----
    const int e = bid;
    const float4 k4 = *(const float4*)(keys + e * D_N + 4 * t);
    const float4 l4 = *(const float4*)(lsig + 4 * t);
    float4 s4;
    s4.x = expf(-l4.x); s4.y = expf(-l4.y); s4.z = expf(-l4.z); s4.w = expf(-l4.w);
    if (e == 0) *(float4*)(sinv + 4 * t) = s4;
    const float4 sk4 = make_float4(s4.x * k4.x, s4.y * k4.y, s4.z * k4.z, s4.w * k4.w);
    bf16x4 skb;
    skb[0] = (__bf16)sk4.x; skb[1] = (__bf16)sk4.y; skb[2] = (__bf16)sk4.z; skb[3] = (__bf16)sk4.w;
    *(bf16x4*)(sk + e * D_N + 4 * t) = skb;
    float p = sk4.x * k4.x + sk4.y * k4.y + sk4.z * k4.z + sk4.w * k4.w;
    #pragma unroll
    for (int off = 32; off > 0; off >>= 1) p += __shfl_down(p, off);
    if ((t & 63) == 0) red[t >> 6] = p;
    __syncthreads();
    if (t == 0) ak[e] = red[0] + red[1] + red[2] + red[3];
  } else {
    // ---- transpose: kT[d][e] = (bf16) keys[e][d], 64-d slab per block ----
    const int d0 = (bid - 64) * 64;
    #pragma unroll
    for (int p = 0; p < 4; ++p) {
      const int e  = p * 16 + (t >> 4);
      const int dd = (t & 15) * 4;
      const float4 k4 = *(const float4*)(keys + (size_t)e * D_N + d0 + dd);
      tl[dd + 0][e] = (__bf16)k4.x; tl[dd + 1][e] = (__bf16)k4.y;
      tl[dd + 2][e] = (__bf16)k4.z; tl[dd + 3][e] = (__bf16)k4.w;
    }
    __syncthreads();
    #pragma unroll
    for (int p = 0; p < 2; ++p) {
      const int dd = p * 32 + (t >> 3);
      const int l8 = t & 7;
      const bf16x8 v = *(const bf16x8*)&tl[dd][l8 * 8];
      *(bf16x8*)(kT + (size_t)(d0 + dd) * E_N + l8 * 8) = v;
    }
  }
}

__global__ __launch_bounds__(256) void main_kernel(
    const float* __restrict__ z, const float* __restrict__ sinv,
    const float* __restrict__ ak, const __bf16* __restrict__ sk,
    const __bf16* __restrict__ kT,
    float* __restrict__ out_sim, float* __restrict__ out_we)
{
  constexpr int ZS = D_N + 8;            // bf16 elems; 16B-aligned rows, breaks bank pattern
  __shared__ __bf16 zlds[ROWS * ZS];     // 16.5 KB
  __shared__ float azs[ROWS];
  __shared__ float simb[ROWS][68];       // +4 pad
  __shared__ __bf16 wlds[ROWS][72];      // +8 pad
  __shared__ float estage[4][ROWS][64];  // per-wave store-coalescing slab (8 KB)

  const int t  = threadIdx.x;
  const int b0 = blockIdx.x * ROWS;

  // ---------- stage z -> bf16 LDS; Az = sum s*z^2 (32 threads per row) ----------
  const int sr = t >> 5;                 // row 0..7
  const int sc = t & 31;
  const float* zrow = z + (size_t)(b0 + sr) * D_N;
  float az = 0.f;
  #pragma unroll
  for (int l = 0; l < 8; ++l) {
    const int c = sc * 4 + l * 128;
    const float4 z4 = *(const float4*)(zrow + c);
    const float4 s4 = *(const float4*)(sinv + c);
    az += s4.x * z4.x * z4.x + s4.y * z4.y * z4.y + s4.z * z4.z * z4.z + s4.w * z4.w * z4.w;
    bf16x4 zb;
    zb[0] = (__bf16)z4.x; zb[1] = (__bf16)z4.y; zb[2] = (__bf16)z4.z; zb[3] = (__bf16)z4.w;
    *(bf16x4*)(&zlds[sr * ZS + c]) = zb;
  }
  az += __shfl_down(az, 16); az += __shfl_down(az, 8);
  az += __shfl_down(az, 4);  az += __shfl_down(az, 2);
  az += __shfl_down(az, 1);
  if (sc == 0) azs[sr] = az;
  __syncthreads();

  // ---------- GEMM1: G[8 rows][64 experts], one 16-expert tile per wave ----------
  const int wave = t >> 6;
  const int lane = t & 63;
  const int ln = lane & 15;
  const int q  = lane >> 4;

  f32x4 acc = {0.f, 0.f, 0.f, 0.f};
  const __bf16* bp = sk + (size_t)(wave * 16 + ln) * D_N + q * 8;
  const __bf16* ap = &zlds[(ln & 7) * ZS + q * 8];   // rows 8..15 wrap; C rows 8..15 discarded
  #pragma unroll 8
  for (int ks = 0; ks < 32; ++ks) {
    const bf16x8 bfr = *(const bf16x8*)(bp + ks * 32);
    const bf16x8 afr = *(const bf16x8*)(ap + ks * 32);
    acc = __builtin_amdgcn_mfma_f32_16x16x32_bf16(afr, bfr, acc, 0, 0, 0);
  }
  const float akv = ak[wave * 16 + ln];
  if (q < 2) {
    #pragma unroll
    for (int i = 0; i < 4; ++i) {
      const int row = q * 4 + i;         // C: row = quad*4+reg, col = lane&15
      const float dist = azs[row] + akv - 2.0f * acc[i];
      simb[row][wave * 16 + ln] = 1.0f / (1.0f + dist);
    }
  }
  __syncthreads();

  // ---------- softmax over e (threads 0..31: 4 lanes per row) ----------
  if (t < 32) {
    const int row = t >> 2, seg = t & 3;
    float v[16];
    #pragma unroll
    for (int i = 0; i < 16; ++i) v[i] = simb[row][seg * 16 + i];
    float mx = v[0];
    #pragma unroll
    for (int i = 1; i < 16; ++i) mx = fmaxf(mx, v[i]);
    mx = fmaxf(mx, __shfl_xor(mx, 1));
    mx = fmaxf(mx, __shfl_xor(mx, 2));
    float sum = 0.f;
    #pragma unroll
    for (int i = 0; i < 16; ++i) { v[i] = __expf(v[i] - mx); sum += v[i]; }
    sum += __shfl_xor(sum, 1);
    sum += __shfl_xor(sum, 2);
    const float inv = 1.0f / sum;
    #pragma unroll
    for (int i = 0; i < 16; ++i) wlds[row][seg * 16 + i] = (__bf16)(v[i] * inv);
  }
  __syncthreads();

  // ---------- similarity -> global (coalesced float4, threads 0..127) ----------
  if (t < 128) {
    const float4 sv = *(const float4*)&simb[t >> 4][(t & 15) * 4];
    *(float4*)(out_sim + (size_t)(b0 + (t >> 4)) * E_N + (t & 15) * 4) = sv;
  }

  // ---------- GEMM2: out[8 rows][1024] = w[8][64] @ keys[64][1024] ----------
  const bf16x8 a0 = *(const bf16x8*)&wlds[ln & 7][q * 8];
  const bf16x8 a1 = *(const bf16x8*)&wlds[ln & 7][32 + q * 8];
  #pragma unroll
  for (int g = 0; g < 4; ++g) {
    #pragma unroll
    for (int i2 = 0; i2 < 4; ++i2) {
      const int dt = wave * 16 + g * 4 + i2;       // wave owns contiguous 256-col slab
      const int d0 = dt * 16;
      const __bf16* kp = kT + (size_t)(d0 + ln) * E_N + q * 8;
      const bf16x8 b0f = *(const bf16x8*)(kp);
      const bf16x8 b1f = *(const bf16x8*)(kp + 32);
      f32x4 o = {0.f, 0.f, 0.f, 0.f};
      o = __builtin_amdgcn_mfma_f32_16x16x32_bf16(a0, b0f, o, 0, 0, 0);
      o = __builtin_amdgcn_mfma_f32_16x16x32_bf16(a1, b1f, o, 0, 0, 0);
      if (q < 2) {
        #pragma unroll
        for (int j = 0; j < 4; ++j)
          estage[wave][q * 4 + j][i2 * 16 + ln] = o[j];
      }
    }
    __builtin_amdgcn_wave_barrier();     // per-wave slab: intra-wave LDS ordering suffices
    #pragma unroll
    for (int j2 = 0; j2 < 2; ++j2) {
      const int f = j2 * 256 + lane * 4;
      const int row = f >> 6, col = f & 63;
      const float4 v = *(const float4*)&estage[wave][row][col];
      *(float4*)(out_we + (size_t)(b0 + row) * D_N + wave * 256 + g * 64 + col) = v;
    }
    __builtin_amdgcn_wave_barrier();
  }
}

extern "C" void kernel_launch(void* const* d_in, const int* in_sizes, int n_in,
                              void* d_out, int out_size, void* d_ws, size_t ws_size,
                              hipStream_t stream)
{
  const float* z    = (const float*)d_in[0];
  const float* keys = (const float*)d_in[1];
  const float* ls   = (const float*)d_in[2];
  float* out_sim = (float*)d_out;
  float* out_we  = out_sim + (size_t)B_N * E_N;
  char* ws = (char*)d_ws;
  float*  sinv = (float*)(ws);
  float*  ak   = (float*)(ws + 4096);
  __bf16* sk   = (__bf16*)(ws + 4352);
  __bf16* kT   = (__bf16*)(ws + 135424);
  prep_kernel<<<80, 256, 0, stream>>>(keys, ls, sinv, ak, sk, kT);
  main_kernel<<<B_N / ROWS, 256, 0, stream>>>(z, sinv, ak, sk, kT, out_sim, out_we);
}

// Round 3
// 83.553 us; speedup vs baseline: 1.0667x; 1.0667x over previous
//
#include <hip/hip_runtime.h>
#include <hip/hip_bf16.h>

#define B_N 4096
#define E_N 64
#define D_N 1024
#define ROWS 16

typedef __bf16 bf16x8 __attribute__((ext_vector_type(8)));
typedef __bf16 bf16x4 __attribute__((ext_vector_type(4)));
typedef float f32x4 __attribute__((ext_vector_type(4)));

// ws layout (bytes):
// [0, 4096)        sinv   (1024 f32)
// [4096, 4352)     Ak     (64 f32)
// [4352, 135424)   sk_bf16 [64][1024]   (sigma_inv * keys, K-major)
// [135424, 266496) kT_bf16 [1024][64]   (raw keys transposed, K(=e)-major)

__global__ __launch_bounds__(256) void prep_kernel(
    const float* __restrict__ keys, const float* __restrict__ lsig,
    float* __restrict__ sinv, float* __restrict__ ak,
    __bf16* __restrict__ sk, __bf16* __restrict__ kT)
{
  __shared__ float red[4];
  __shared__ __bf16 tl[64][72];          // transpose tile, +8 pad
  const int bid = blockIdx.x;
  const int t = threadIdx.x;

  if (bid < 64) {
    // ---- per-expert: sinv, sk = sinv*keys (bf16), Ak = sum sinv*k^2 ----
    const int e = bid;
    const float4 k4 = *(const float4*)(keys + e * D_N + 4 * t);
    const float4 l4 = *(const float4*)(lsig + 4 * t);
    float4 s4;
    s4.x = expf(-l4.x); s4.y = expf(-l4.y); s4.z = expf(-l4.z); s4.w = expf(-l4.w);
    if (e == 0) *(float4*)(sinv + 4 * t) = s4;
    const float4 sk4 = make_float4(s4.x * k4.x, s4.y * k4.y, s4.z * k4.z, s4.w * k4.w);
    bf16x4 skb;
    skb[0] = (__bf16)sk4.x; skb[1] = (__bf16)sk4.y; skb[2] = (__bf16)sk4.z; skb[3] = (__bf16)sk4.w;
    *(bf16x4*)(sk + e * D_N + 4 * t) = skb;
    float p = sk4.x * k4.x + sk4.y * k4.y + sk4.z * k4.z + sk4.w * k4.w;
    #pragma unroll
    for (int off = 32; off > 0; off >>= 1) p += __shfl_down(p, off);
    if ((t & 63) == 0) red[t >> 6] = p;
    __syncthreads();
    if (t == 0) ak[e] = red[0] + red[1] + red[2] + red[3];
  } else {
    // ---- transpose: kT[d][e] = (bf16) keys[e][d], 64-d slab per block ----
    const int d0 = (bid - 64) * 64;
    #pragma unroll
    for (int p = 0; p < 4; ++p) {
      const int e  = p * 16 + (t >> 4);
      const int dd = (t & 15) * 4;
      const float4 k4 = *(const float4*)(keys + (size_t)e * D_N + d0 + dd);
      tl[dd + 0][e] = (__bf16)k4.x; tl[dd + 1][e] = (__bf16)k4.y;
      tl[dd + 2][e] = (__bf16)k4.z; tl[dd + 3][e] = (__bf16)k4.w;
    }
    __syncthreads();
    #pragma unroll
    for (int p = 0; p < 2; ++p) {
      const int dd = p * 32 + (t >> 3);
      const int l8 = t & 7;
      const bf16x8 v = *(const bf16x8*)&tl[dd][l8 * 8];
      *(bf16x8*)(kT + (size_t)(d0 + dd) * E_N + l8 * 8) = v;
    }
  }
}

__global__ __launch_bounds__(256) void main_kernel(
    const float* __restrict__ z, const float* __restrict__ sinv,
    const float* __restrict__ ak, const __bf16* __restrict__ sk,
    const __bf16* __restrict__ kT,
    float* __restrict__ out_sim, float* __restrict__ out_we)
{
  constexpr int ZS = D_N + 8;            // bf16 elems; 16B-aligned rows, breaks bank pattern
  __shared__ __bf16 zlds[ROWS * ZS];     // 33 KB
  __shared__ float azs[ROWS];
  __shared__ float simb[ROWS][68];       // +4 pad
  __shared__ __bf16 wlds[ROWS][72];      // +8 pad

  const int t  = threadIdx.x;
  const int b0 = blockIdx.x * ROWS;

  // ---------- stage z -> bf16 LDS; Az = sum s*z^2 (16 threads per row) ----------
  const int sr = t >> 4;                 // row 0..15
  const int sc = t & 15;
  const float* zrow = z + (size_t)(b0 + sr) * D_N;
  float az = 0.f;
  #pragma unroll
  for (int l = 0; l < 16; ++l) {
    const int c = sc * 4 + l * 64;
    const float4 z4 = *(const float4*)(zrow + c);
    const float4 s4 = *(const float4*)(sinv + c);
    az += s4.x * z4.x * z4.x + s4.y * z4.y * z4.y + s4.z * z4.z * z4.z + s4.w * z4.w * z4.w;
    bf16x4 zb;
    zb[0] = (__bf16)z4.x; zb[1] = (__bf16)z4.y; zb[2] = (__bf16)z4.z; zb[3] = (__bf16)z4.w;
    *(bf16x4*)(&zlds[sr * ZS + c]) = zb;
  }
  // reduce across the 16 lanes of this row (lanes sr*16..sr*16+15 are contiguous)
  az += __shfl_xor(az, 1); az += __shfl_xor(az, 2);
  az += __shfl_xor(az, 4); az += __shfl_xor(az, 8);
  if (sc == 0) azs[sr] = az;
  __syncthreads();                       // zlds + azs ready

  // ---------- GEMM1: G[16 rows][64 experts], one 16-expert tile per wave ----------
  const int wave = t >> 6;
  const int lane = t & 63;
  const int ln = lane & 15;
  const int q  = lane >> 4;

  const float akv = ak[wave * 16 + ln];
  f32x4 acc = {0.f, 0.f, 0.f, 0.f};
  const __bf16* bp = sk + (size_t)(wave * 16 + ln) * D_N + q * 8;
  const __bf16* ap = &zlds[ln * ZS + q * 8];
  #pragma unroll 8
  for (int ks = 0; ks < 32; ++ks) {
    const bf16x8 bfr = *(const bf16x8*)(bp + ks * 32);
    const bf16x8 afr = *(const bf16x8*)(ap + ks * 32);
    acc = __builtin_amdgcn_mfma_f32_16x16x32_bf16(afr, bfr, acc, 0, 0, 0);
  }

  #pragma unroll
  for (int i = 0; i < 4; ++i) {
    const int row = q * 4 + i;           // C: row = quad*4+reg, col = lane&15
    const float dist = azs[row] + akv - 2.0f * acc[i];
    simb[row][wave * 16 + ln] = 1.0f / (1.0f + dist);
  }

  // prefetch GEMM2's first B-frag group (global kT, no LDS dependency) so the
  // vmcnt overlaps the softmax serialization below
  const __bf16* kp0 = kT + (size_t)(wave * 16 + ln) * E_N + q * 8;
  const bf16x8 pb0 = *(const bf16x8*)(kp0);
  const bf16x8 pb1 = *(const bf16x8*)(kp0 + 32);

  __syncthreads();                       // simb ready

  // ---------- softmax over e (threads 0..63: 4 lanes per row) ----------
  if (t < 64) {
    const int row = t >> 2, seg = t & 3;
    float v[16];
    #pragma unroll
    for (int i = 0; i < 16; ++i) v[i] = simb[row][seg * 16 + i];
    float mx = v[0];
    #pragma unroll
    for (int i = 1; i < 16; ++i) mx = fmaxf(mx, v[i]);
    mx = fmaxf(mx, __shfl_xor(mx, 1));
    mx = fmaxf(mx, __shfl_xor(mx, 2));
    float sum = 0.f;
    #pragma unroll
    for (int i = 0; i < 16; ++i) { v[i] = __expf(v[i] - mx); sum += v[i]; }
    sum += __shfl_xor(sum, 1);
    sum += __shfl_xor(sum, 2);
    const float inv = 1.0f / sum;
    #pragma unroll
    for (int i = 0; i < 16; ++i) wlds[row][seg * 16 + i] = (__bf16)(v[i] * inv);
  }
  __syncthreads();                       // wlds ready

  // ---------- similarity -> global (coalesced float4) ----------
  {
    const float4 sv = *(const float4*)&simb[t >> 4][(t & 15) * 4];
    *(float4*)(out_sim + (size_t)(b0 + (t >> 4)) * E_N + (t & 15) * 4) = sv;
  }

  // ---------- GEMM2: out[16 rows][1024] = w[16][64] @ keys[64][1024] ----------
  const bf16x8 a0 = *(const bf16x8*)&wlds[ln][q * 8];        // A: m=row, k=e
  const bf16x8 a1 = *(const bf16x8*)&wlds[ln][32 + q * 8];
  #pragma unroll
  for (int i = 0; i < 16; ++i) {
    const int dt = wave + 4 * i;
    const int d0 = dt * 16;
    bf16x8 b0f, b1f;
    if (i == 0) { b0f = pb0; b1f = pb1; }
    else {
      const __bf16* kp = kT + (size_t)(d0 + ln) * E_N + q * 8;
      b0f = *(const bf16x8*)(kp);
      b1f = *(const bf16x8*)(kp + 32);
    }
    f32x4 o = {0.f, 0.f, 0.f, 0.f};
    o = __builtin_amdgcn_mfma_f32_16x16x32_bf16(a0, b0f, o, 0, 0, 0);
    o = __builtin_amdgcn_mfma_f32_16x16x32_bf16(a1, b1f, o, 0, 0, 0);
    #pragma unroll
    for (int j = 0; j < 4; ++j)
      out_we[(size_t)(b0 + q * 4 + j) * D_N + d0 + ln] = o[j];
  }
}

extern "C" void kernel_launch(void* const* d_in, const int* in_sizes, int n_in,
                              void* d_out, int out_size, void* d_ws, size_t ws_size,
                              hipStream_t stream)
{
  const float* z    = (const float*)d_in[0];
  const float* keys = (const float*)d_in[1];
  const float* ls   = (const float*)d_in[2];
  float* out_sim = (float*)d_out;
  float* out_we  = out_sim + (size_t)B_N * E_N;
  char* ws = (char*)d_ws;
  float*  sinv = (float*)(ws);
  float*  ak   = (float*)(ws + 4096);
  __bf16* sk   = (__bf16*)(ws + 4352);
  __bf16* kT   = (__bf16*)(ws + 135424);
  prep_kernel<<<80, 256, 0, stream>>>(keys, ls, sinv, ak, sk, kT);
  main_kernel<<<B_N / ROWS, 256, 0, stream>>>(z, sinv, ak, sk, kT, out_sim, out_we);
}